// Round 1
// baseline (215.163 us; speedup 1.0000x reference)
//
#include <hip/hip_runtime.h>

#define NMODELS 64
#define BBATCH  4096
#define IN_DIM  64
#define H_DIM   256

typedef __attribute__((ext_vector_type(8))) short short8;
typedef __attribute__((ext_vector_type(4))) float floatx4;

__device__ __forceinline__ unsigned short f2bf(float f) {
    unsigned int u = __builtin_bit_cast(unsigned int, f);
    u += 0x7FFFu + ((u >> 16) & 1u);          // RNE (finite data, no NaN handling needed)
    return (unsigned short)(u >> 16);
}

// Transpose + fp32->bf16: src [M][K][N] fp32  ->  dst [M][N][K] bf16
// grid = M * (K/64) * (N/64), block = 256
__global__ __launch_bounds__(256) void transpose_cvt(const float* __restrict__ src,
                                                     unsigned short* __restrict__ dst,
                                                     int K, int N) {
    __shared__ float lds[64 * 65];
    const int kt = K >> 6, nt = N >> 6;
    const int t = blockIdx.x;
    const int m = t / (kt * nt);
    const int rem = t - m * (kt * nt);
    const int kb = rem / nt, nb = rem - kb * nt;
    const int tid = threadIdx.x;
    const int c = tid & 63, rq = tid >> 6;

    const float* s = src + ((size_t)m * K + (size_t)kb * 64) * N + nb * 64;
#pragma unroll
    for (int it = 0; it < 16; ++it) {
        int r = it * 4 + rq;
        lds[c * 65 + r] = s[(size_t)r * N + c];   // lds[n_local][k_local]
    }
    __syncthreads();
    unsigned short* d = dst + ((size_t)m * N + (size_t)nb * 64) * K + kb * 64;
#pragma unroll
    for (int it = 0; it < 16; ++it) {
        int n = it * 4 + rq;
        d[(size_t)n * K + c] = f2bf(lds[n * 65 + c]);
    }
}

// Fused 3-layer MLP. One WG per (model m, 64-row batch tile).
// Wave w owns H-columns [64w, 64w+64). h1 lives in swizzled bf16 LDS; h2 in regs.
__global__ __launch_bounds__(256, 2) void mlp_fused(
    const float* __restrict__ xs,
    const unsigned short* __restrict__ w1t,   // [M][H][IN] bf16
    const float* __restrict__ b1,
    const unsigned short* __restrict__ w2t,   // [M][H][H] bf16 (n-major)
    const float* __restrict__ b2,
    const float* __restrict__ w3,             // [M][H][1]
    const float* __restrict__ b3,             // [M][1]
    float* __restrict__ out)                  // [M][B][1]
{
    __shared__ unsigned short h1s[64 * 256];  // 32 KB, XOR-swizzled on 16B chunks
    __shared__ float red[4][64];              // cross-wave layer-3 reduce

    const int bid = blockIdx.x;
    const int m   = bid >> 6;        // 64 tiles per model -> per-XCD L2 keeps W2t hot
    const int tb  = bid & 63;
    const int tid = threadIdx.x;
    const int w   = tid >> 6;
    const int lane = tid & 63;
    const int q   = lane >> 4;
    const int c16 = lane & 15;
    const int sw  = c16 & 7;         // swizzle key for A-frag rows (row&7 == c16&7)

    // ---------------- Phase 1: h1 = relu(x @ W1 + b1) ----------------
    const float* xrow = xs + ((size_t)m * BBATCH + (size_t)tb * 64) * IN_DIM;
    const unsigned short* w1p = w1t + (size_t)m * (H_DIM * IN_DIM)
                                + (w * 64 + c16) * IN_DIM + q * 8;

    short8 ax[4][2];
#pragma unroll
    for (int rb = 0; rb < 4; ++rb)
#pragma unroll
        for (int kb = 0; kb < 2; ++kb) {
            const float* xp = xrow + (rb * 16 + c16) * IN_DIM + kb * 32 + q * 8;
            float4 v0 = *(const float4*)xp;
            float4 v1 = *(const float4*)(xp + 4);
            short8 a;
            a[0] = (short)f2bf(v0.x); a[1] = (short)f2bf(v0.y);
            a[2] = (short)f2bf(v0.z); a[3] = (short)f2bf(v0.w);
            a[4] = (short)f2bf(v1.x); a[5] = (short)f2bf(v1.y);
            a[6] = (short)f2bf(v1.z); a[7] = (short)f2bf(v1.w);
            ax[rb][kb] = a;
        }

    floatx4 acc[4][4];
#pragma unroll
    for (int rb = 0; rb < 4; ++rb)
#pragma unroll
        for (int nb = 0; nb < 4; ++nb)
            acc[rb][nb] = (floatx4){0.f, 0.f, 0.f, 0.f};

#pragma unroll
    for (int kb = 0; kb < 2; ++kb) {
        short8 bw[4];
#pragma unroll
        for (int nb = 0; nb < 4; ++nb)
            bw[nb] = *(const short8*)(w1p + nb * (16 * IN_DIM) + kb * 32);
#pragma unroll
        for (int nb = 0; nb < 4; ++nb)
#pragma unroll
            for (int rb = 0; rb < 4; ++rb)
                acc[rb][nb] = __builtin_amdgcn_mfma_f32_16x16x32_bf16(
                    ax[rb][kb], bw[nb], acc[rb][nb], 0, 0, 0);
    }

    const int ncol = w * 64 + c16;   // + nb*16 gives this lane's h-column
    {
        float b1v[4];
#pragma unroll
        for (int nb = 0; nb < 4; ++nb) b1v[nb] = b1[m * H_DIM + ncol + nb * 16];
#pragma unroll
        for (int rb = 0; rb < 4; ++rb)
#pragma unroll
            for (int nb = 0; nb < 4; ++nb)
#pragma unroll
                for (int r = 0; r < 4; ++r) {
                    float v = fmaxf(acc[rb][nb][r] + b1v[nb], 0.f);
                    int row = rb * 16 + q * 4 + r;
                    int col = ncol + nb * 16;
                    int phys = row * 256 + ((((col >> 3) ^ (row & 7)) << 3) | (col & 7));
                    h1s[phys] = f2bf(v);
                }
    }
    __syncthreads();

    // ---------------- Phase 2: h2 = relu(h1 @ W2 + b2), in registers ----------------
#pragma unroll
    for (int rb = 0; rb < 4; ++rb)
#pragma unroll
        for (int nb = 0; nb < 4; ++nb)
            acc[rb][nb] = (floatx4){0.f, 0.f, 0.f, 0.f};

    const unsigned short* w2p = w2t + (size_t)m * (H_DIM * H_DIM)
                                + (w * 64 + c16) * H_DIM + q * 8;
#pragma unroll
    for (int kb = 0; kb < 8; ++kb) {
        short8 av[4], bv[4];
#pragma unroll
        for (int rb = 0; rb < 4; ++rb)
            av[rb] = *(const short8*)&h1s[(rb * 16 + c16) * 256 + (((kb * 4 + q) ^ sw) << 3)];
#pragma unroll
        for (int nb = 0; nb < 4; ++nb)
            bv[nb] = *(const short8*)(w2p + nb * (16 * H_DIM) + kb * 32);
#pragma unroll
        for (int nb = 0; nb < 4; ++nb)
#pragma unroll
            for (int rb = 0; rb < 4; ++rb)
                acc[rb][nb] = __builtin_amdgcn_mfma_f32_16x16x32_bf16(
                    av[rb], bv[nb], acc[rb][nb], 0, 0, 0);
    }

    // ---------------- Phase 3: out = h2 @ W3 + b3 (OUT=1, never materialize h2) ----
    float b2v[4], w3v[4];
#pragma unroll
    for (int nb = 0; nb < 4; ++nb) {
        b2v[nb] = b2[m * H_DIM + ncol + nb * 16];
        w3v[nb] = w3[m * H_DIM + ncol + nb * 16];
    }
    float p[4][4];
#pragma unroll
    for (int rb = 0; rb < 4; ++rb)
#pragma unroll
        for (int r = 0; r < 4; ++r) p[rb][r] = 0.f;
#pragma unroll
    for (int rb = 0; rb < 4; ++rb)
#pragma unroll
        for (int nb = 0; nb < 4; ++nb)
#pragma unroll
            for (int r = 0; r < 4; ++r) {
                float v = fmaxf(acc[rb][nb][r] + b2v[nb], 0.f);
                p[rb][r] += v * w3v[nb];
            }
    // reduce over the 16 lanes (c16) of each quad
#pragma unroll
    for (int off = 1; off < 16; off <<= 1)
#pragma unroll
        for (int rb = 0; rb < 4; ++rb)
#pragma unroll
            for (int r = 0; r < 4; ++r)
                p[rb][r] += __shfl_xor(p[rb][r], off);

    if (c16 == 0) {
#pragma unroll
        for (int rb = 0; rb < 4; ++rb)
#pragma unroll
            for (int r = 0; r < 4; ++r)
                red[w][rb * 16 + q * 4 + r] = p[rb][r];
    }
    __syncthreads();
    if (tid < 64) {
        float s = red[0][tid] + red[1][tid] + red[2][tid] + red[3][tid] + b3[m];
        out[(size_t)m * BBATCH + tb * 64 + tid] = s;
    }
}

extern "C" void kernel_launch(void* const* d_in, const int* in_sizes, int n_in,
                              void* d_out, int out_size, void* d_ws, size_t ws_size,
                              hipStream_t stream) {
    const float* xs = (const float*)d_in[0];
    const float* W1 = (const float*)d_in[1];
    const float* b1 = (const float*)d_in[2];
    const float* W2 = (const float*)d_in[3];
    const float* b2 = (const float*)d_in[4];
    const float* W3 = (const float*)d_in[5];
    const float* b3 = (const float*)d_in[6];
    float* out = (float*)d_out;

    unsigned short* w1t = (unsigned short*)d_ws;                    // M*H*IN bf16 = 2 MB
    unsigned short* w2t = w1t + (size_t)NMODELS * H_DIM * IN_DIM;   // M*H*H bf16 = 8.4 MB

    transpose_cvt<<<NMODELS * 1 * 4, 256, 0, stream>>>(W1, w1t, IN_DIM, H_DIM);
    transpose_cvt<<<NMODELS * 4 * 4, 256, 0, stream>>>(W2, w2t, H_DIM, H_DIM);
    mlp_fused<<<NMODELS * (BBATCH / 64), 256, 0, stream>>>(xs, w1t, b1, w2t, b2, W3, b3, out);
}

// Round 2
// 208.516 us; speedup vs baseline: 1.0319x; 1.0319x over previous
//
#include <hip/hip_runtime.h>

#define NMODELS 64
#define BBATCH  4096
#define IN_DIM  64
#define H_DIM   256

typedef __attribute__((ext_vector_type(8))) short short8;
typedef __attribute__((ext_vector_type(4))) short short4v;
typedef __attribute__((ext_vector_type(4))) float floatx4;

__device__ __forceinline__ unsigned short f2bf(float f) {
    unsigned int u = __builtin_bit_cast(unsigned int, f);
    return (unsigned short)((u + 0x8000u) >> 16);   // round-half-up: 1 VALU op, 0.5-ulp bound
}

// Fused transpose+cvt prep: W1 [M][64][256] -> w1t [M][256][64] bf16 (blocks 0..255)
//                           W2 [M][256][256] -> w2t [M][256][256] bf16 (blocks 256..1279)
__global__ __launch_bounds__(256) void prep_weights(const float* __restrict__ W1,
                                                    const float* __restrict__ W2,
                                                    unsigned short* __restrict__ w1t,
                                                    unsigned short* __restrict__ w2t) {
    __shared__ float lds[64][65];
    const int bid = blockIdx.x;
    const float* src;
    unsigned short* dst;
    int K, N, m, kb, nb;
    if (bid < 256) {
        m = bid >> 2; kb = 0; nb = bid & 3; K = IN_DIM; N = H_DIM;
        src = W1; dst = w1t;
    } else {
        int t = bid - 256;
        m = t >> 4; kb = (t >> 2) & 3; nb = t & 3; K = H_DIM; N = H_DIM;
        src = W2; dst = w2t;
    }
    const float* s = src + ((size_t)m * K + (size_t)kb * 64) * N + nb * 64;
    const int tid = threadIdx.x;
    const int r = tid >> 4, c4 = (tid & 15) * 4;
#pragma unroll
    for (int p = 0; p < 4; ++p) {
        int row = p * 16 + r;                      // k-local
        float4 v = *(const float4*)(s + (size_t)row * N + c4);
        lds[row][c4] = v.x; lds[row][c4 + 1] = v.y;
        lds[row][c4 + 2] = v.z; lds[row][c4 + 3] = v.w;
    }
    __syncthreads();
    const int n = tid & 63, kg = tid >> 6;         // each thread packs 16 k for one n
    unsigned short tmp[16];
#pragma unroll
    for (int j = 0; j < 16; ++j) tmp[j] = f2bf(lds[kg * 16 + j][n]);
    unsigned short* d = dst + ((size_t)m * N + (size_t)(nb * 64 + n)) * K + kb * 64 + kg * 16;
    *(short8*)d = *(const short8*)tmp;
    *(short8*)(d + 8) = *(const short8*)(tmp + 8);
}

// Fused 3-layer MLP. One WG per (model m, 64-row batch tile); wave w owns
// h-columns {w*64 + c16*4 + nb} (n->col permutation makes epilogue stores and
// bias loads contiguous). h1 in 32 KB XOR-swizzled LDS; h2 in regs; OUT=1
// reduced via shfl + LDS overlay.
__global__ __launch_bounds__(256, 4) void mlp_fused(
    const float* __restrict__ xs,
    const unsigned short* __restrict__ w1t,   // [M][H][IN] bf16
    const float* __restrict__ b1,
    const unsigned short* __restrict__ w2t,   // [M][H][H] bf16 (n-major)
    const float* __restrict__ b2,
    const float* __restrict__ w3,             // [M][H]
    const float* __restrict__ b3,             // [M]
    float* __restrict__ out)                  // [M][B]
{
    __shared__ unsigned short h1s[64 * 256];  // 32 KB exactly -> 5 WGs/CU
    float* red = (float*)h1s;                 // overlay for cross-wave reduce (after barrier)

    const int bid = blockIdx.x;
    const int m   = bid >> 6;                 // tiles of one model adjacent -> W2 L2-hot
    const int tb  = bid & 63;
    const int tid = threadIdx.x;
    const int w   = tid >> 6;
    const int lane = tid & 63;
    const int q   = lane >> 4;
    const int c16 = lane & 15;
    const int sw  = c16 & 7;                  // phase-2 A-read swizzle key (row&7)

    // ---------------- Phase 1: h1 = relu(x @ W1 + b1) ----------------
    const float* xrow = xs + ((size_t)m * BBATCH + (size_t)tb * 64) * IN_DIM;
    const unsigned short* w1p = w1t + (size_t)m * (H_DIM * IN_DIM)
                                + (w * 64 + c16 * 4) * IN_DIM + q * 8;

    short8 ax[4][2];
#pragma unroll
    for (int rb = 0; rb < 4; ++rb)
#pragma unroll
        for (int kb = 0; kb < 2; ++kb) {
            const float* xp = xrow + (rb * 16 + c16) * IN_DIM + kb * 32 + q * 8;
            float4 v0 = *(const float4*)xp;
            float4 v1 = *(const float4*)(xp + 4);
            short8 a;
            a[0] = (short)f2bf(v0.x); a[1] = (short)f2bf(v0.y);
            a[2] = (short)f2bf(v0.z); a[3] = (short)f2bf(v0.w);
            a[4] = (short)f2bf(v1.x); a[5] = (short)f2bf(v1.y);
            a[6] = (short)f2bf(v1.z); a[7] = (short)f2bf(v1.w);
            ax[rb][kb] = a;
        }

    floatx4 acc[4][4];
#pragma unroll
    for (int rb = 0; rb < 4; ++rb)
#pragma unroll
        for (int nb = 0; nb < 4; ++nb)
            acc[rb][nb] = (floatx4){0.f, 0.f, 0.f, 0.f};

#pragma unroll
    for (int kb = 0; kb < 2; ++kb) {
        short8 bw[4];
#pragma unroll
        for (int nb = 0; nb < 4; ++nb)
            bw[nb] = *(const short8*)(w1p + nb * IN_DIM + kb * 32);
#pragma unroll
        for (int nb = 0; nb < 4; ++nb)
#pragma unroll
            for (int rb = 0; rb < 4; ++rb)
                acc[rb][nb] = __builtin_amdgcn_mfma_f32_16x16x32_bf16(
                    ax[rb][kb], bw[nb], acc[rb][nb], 0, 0, 0);
    }

    // epilogue: bias+relu+cvt, contiguous short4 per (rb,r), 16B-chunk XOR swizzle
    {
        floatx4 b1v = *(const floatx4*)(b1 + m * H_DIM + w * 64 + c16 * 4);
#pragma unroll
        for (int rb = 0; rb < 4; ++rb)
#pragma unroll
            for (int r = 0; r < 4; ++r) {
                short4v t;
#pragma unroll
                for (int nb = 0; nb < 4; ++nb)
                    t[nb] = (short)f2bf(fmaxf(acc[rb][nb][r] + b1v[nb], 0.f));
                int row = rb * 16 + q * 4 + r;
                int chunk = (w * 8 + (c16 >> 1)) ^ (row & 7);
                *(short4v*)((char*)h1s + row * 512 + chunk * 16 + (c16 & 1) * 8) = t;
            }
    }
    __syncthreads();

    // ---------------- Phase 2: h2 = relu(h1 @ W2 + b2), in registers ----------------
#pragma unroll
    for (int rb = 0; rb < 4; ++rb)
#pragma unroll
        for (int nb = 0; nb < 4; ++nb)
            acc[rb][nb] = (floatx4){0.f, 0.f, 0.f, 0.f};

    const unsigned short* w2p = w2t + (size_t)m * (H_DIM * H_DIM)
                                + (w * 64 + c16 * 4) * H_DIM + q * 8;
#pragma unroll
    for (int kb = 0; kb < 8; ++kb) {
        short8 av[4], bv[4];
#pragma unroll
        for (int rb = 0; rb < 4; ++rb)
            av[rb] = *(const short8*)((char*)h1s + (rb * 16 + c16) * 512
                                      + (((kb * 4 + q) ^ sw) * 16));
#pragma unroll
        for (int nb = 0; nb < 4; ++nb)
            bv[nb] = *(const short8*)(w2p + nb * H_DIM + kb * 32);
#pragma unroll
        for (int nb = 0; nb < 4; ++nb)
#pragma unroll
            for (int rb = 0; rb < 4; ++rb)
                acc[rb][nb] = __builtin_amdgcn_mfma_f32_16x16x32_bf16(
                    av[rb], bv[nb], acc[rb][nb], 0, 0, 0);
    }

    // ---------------- Phase 3: out = h2 @ W3 + b3 (OUT=1) ----------------
    floatx4 b2v = *(const floatx4*)(b2 + m * H_DIM + w * 64 + c16 * 4);
    floatx4 w3v = *(const floatx4*)(w3 + m * H_DIM + w * 64 + c16 * 4);
    float p[4][4];
#pragma unroll
    for (int rb = 0; rb < 4; ++rb)
#pragma unroll
        for (int r = 0; r < 4; ++r) p[rb][r] = 0.f;
#pragma unroll
    for (int rb = 0; rb < 4; ++rb)
#pragma unroll
        for (int nb = 0; nb < 4; ++nb)
#pragma unroll
            for (int r = 0; r < 4; ++r) {
                float v = fmaxf(acc[rb][nb][r] + b2v[nb], 0.f);
                p[rb][r] += v * w3v[nb];
            }
#pragma unroll
    for (int off = 1; off < 16; off <<= 1)
#pragma unroll
        for (int rb = 0; rb < 4; ++rb)
#pragma unroll
            for (int r = 0; r < 4; ++r)
                p[rb][r] += __shfl_xor(p[rb][r], off);

    __syncthreads();   // all h1s reads done -> safe to overlay red
    if (c16 == 0) {
#pragma unroll
        for (int rb = 0; rb < 4; ++rb)
#pragma unroll
            for (int r = 0; r < 4; ++r)
                red[w * 64 + rb * 16 + q * 4 + r] = p[rb][r];
    }
    __syncthreads();
    if (tid < 64) {
        float s = red[tid] + red[64 + tid] + red[128 + tid] + red[192 + tid] + b3[m];
        out[(size_t)m * BBATCH + tb * 64 + tid] = s;
    }
}

extern "C" void kernel_launch(void* const* d_in, const int* in_sizes, int n_in,
                              void* d_out, int out_size, void* d_ws, size_t ws_size,
                              hipStream_t stream) {
    const float* xs = (const float*)d_in[0];
    const float* W1 = (const float*)d_in[1];
    const float* b1 = (const float*)d_in[2];
    const float* W2 = (const float*)d_in[3];
    const float* b2 = (const float*)d_in[4];
    const float* W3 = (const float*)d_in[5];
    const float* b3 = (const float*)d_in[6];
    float* out = (float*)d_out;

    unsigned short* w1t = (unsigned short*)d_ws;                    // 2 MB
    unsigned short* w2t = w1t + (size_t)NMODELS * H_DIM * IN_DIM;   // 8.4 MB

    prep_weights<<<256 + NMODELS * 16, 256, 0, stream>>>(W1, W2, w1t, w2t);
    mlp_fused<<<NMODELS * (BBATCH / 64), 256, 0, stream>>>(xs, w1t, b1, w2t, b2, W3, b3, out);
}